// Round 5
// baseline (938.890 us; speedup 1.0000x reference)
//
#include <hip/hip_runtime.h>
#include <cstddef>
#include <cstdint>

#define NN 16384
#define FF 64
#define BM 32               // rows per block (full-K, no split-K)
#define BK 64               // k-chunk
#define NC (NN / BK)        // 256 chunks

typedef __attribute__((ext_vector_type(8))) short bf16x8;
typedef __attribute__((ext_vector_type(4))) float f32x4;
typedef unsigned short ushort_t;

#define GLOBAL_AS __attribute__((address_space(1)))
#define LDS_AS    __attribute__((address_space(3)))

// truncate-split: f = hi + lo (+ ~2^-16 rel dropped); hi/lo as bf16 bit patterns
__device__ __forceinline__ void f32_split(float f, ushort_t& h, ushort_t& l) {
    unsigned u = __builtin_bit_cast(unsigned, f);
    h = (ushort_t)(u >> 16);
    float hf = __builtin_bit_cast(float, u & 0xFFFF0000u);
    float lo = f - hf;                       // exact (Sterbenz)
    l = (ushort_t)(__builtin_bit_cast(unsigned, lo) >> 16);
}

// ---------------------------------------------------------------------------
// Hop 0: Th/Tl = splitT(x) ; out = bias + x @ W0.   grid 256, 64 rows/block.
// ---------------------------------------------------------------------------
__global__ __launch_bounds__(256) void convT_init(
    const float* __restrict__ X, ushort_t* __restrict__ Th,
    ushort_t* __restrict__ Tl, const float* __restrict__ W0,
    const float* __restrict__ bias, float* __restrict__ out)
{
    __shared__ float S[64][68];
    __shared__ float W[64][64];
    const int t = threadIdx.x;
    const int rb = blockIdx.x * 64;
    {
        const int row = t >> 2;
        const int c0 = (t & 3) * 16;
        const float* src = X + (size_t)(rb + row) * FF + c0;
        *(float4*)&S[row][c0 + 0]  = *(const float4*)(src + 0);
        *(float4*)&S[row][c0 + 4]  = *(const float4*)(src + 4);
        *(float4*)&S[row][c0 + 8]  = *(const float4*)(src + 8);
        *(float4*)&S[row][c0 + 12] = *(const float4*)(src + 12);
        float4* wd = (float4*)&W[0][0];
        const float4* ws = (const float4*)W0;
#pragma unroll
        for (int j = 0; j < 4; ++j) wd[t * 4 + j] = ws[t * 4 + j];
    }
    __syncthreads();
    // split-transpose
    {
        const int cc = t >> 2;
        const int r0 = (t & 3) * 16;
        ushort_t hh[16], ll[16];
#pragma unroll
        for (int i = 0; i < 16; ++i) f32_split(S[r0 + i][cc], hh[i], ll[i]);
        unsigned wh[8], wl[8];
#pragma unroll
        for (int j = 0; j < 8; ++j) {
            wh[j] = (unsigned)hh[2 * j] | ((unsigned)hh[2 * j + 1] << 16);
            wl[j] = (unsigned)ll[2 * j] | ((unsigned)ll[2 * j + 1] << 16);
        }
        const size_t o = (size_t)cc * NN + rb + r0;
        *(uint4*)(Th + o)     = make_uint4(wh[0], wh[1], wh[2], wh[3]);
        *(uint4*)(Th + o + 8) = make_uint4(wh[4], wh[5], wh[6], wh[7]);
        *(uint4*)(Tl + o)     = make_uint4(wl[0], wl[1], wl[2], wl[3]);
        *(uint4*)(Tl + o + 8) = make_uint4(wl[4], wl[5], wl[6], wl[7]);
    }
    // out = bias + x@W0 : 2 rows x 8 cols per thread
    {
        const int row0 = (t >> 3) * 2;
        const int col0 = (t & 7) * 8;
        float acc[2][8];
        const float4 b0 = *(const float4*)(bias + col0);
        const float4 b1 = *(const float4*)(bias + col0 + 4);
#pragma unroll
        for (int r = 0; r < 2; ++r) {
            acc[r][0] = b0.x; acc[r][1] = b0.y; acc[r][2] = b0.z; acc[r][3] = b0.w;
            acc[r][4] = b1.x; acc[r][5] = b1.y; acc[r][6] = b1.z; acc[r][7] = b1.w;
        }
#pragma unroll
        for (int f = 0; f < FF; ++f) {
            const float x0 = S[row0][f];
            const float x1 = S[row0 + 1][f];
            const float4 w0 = *(const float4*)&W[f][col0];
            const float4 w1 = *(const float4*)&W[f][col0 + 4];
            acc[0][0] += x0 * w0.x; acc[0][1] += x0 * w0.y;
            acc[0][2] += x0 * w0.z; acc[0][3] += x0 * w0.w;
            acc[0][4] += x0 * w1.x; acc[0][5] += x0 * w1.y;
            acc[0][6] += x0 * w1.z; acc[0][7] += x0 * w1.w;
            acc[1][0] += x1 * w0.x; acc[1][1] += x1 * w0.y;
            acc[1][2] += x1 * w0.z; acc[1][3] += x1 * w0.w;
            acc[1][4] += x1 * w1.x; acc[1][5] += x1 * w1.y;
            acc[1][6] += x1 * w1.z; acc[1][7] += x1 * w1.w;
        }
#pragma unroll
        for (int r = 0; r < 2; ++r) {
            const size_t o = (size_t)(rb + row0 + r) * FF + col0;
            float4 v0, v1;
            v0.x = acc[r][0]; v0.y = acc[r][1]; v0.z = acc[r][2]; v0.w = acc[r][3];
            v1.x = acc[r][4]; v1.y = acc[r][5]; v1.z = acc[r][6]; v1.w = acc[r][7];
            *(float4*)(out + o) = v0;
            *(float4*)(out + o + 4) = v1;
        }
    }
}

// ---------------------------------------------------------------------------
// Fused hop:  t = alpha*(L[rb:rb+32,:] @ T) + beta*Tsub[rb:rb+32]
//             [Tstore] = t ; [Thn/Tln] = splitT(t) ; out += t @ Wk
// grid 512 blocks x 256 thr (4 waves, each 32 rows x 16 cols). Full K.
// ---------------------------------------------------------------------------
__global__ __launch_bounds__(256) void cheb_hop(
    const float* __restrict__ L,
    const ushort_t* __restrict__ Th, const ushort_t* __restrict__ Tl,
    ushort_t* __restrict__ Thn, ushort_t* __restrict__ Tln,
    const float* __restrict__ Tsub, float* __restrict__ Tstore,
    const float* __restrict__ Wk, float* __restrict__ out,
    float alpha, float beta)
{
    __shared__ char smem[49152];
    // A: [2][32*64] ushort (4096 B/slot) hi at 0, lo at 8192
    // B: [2][64*64] ushort (8192 B/slot) hi at 16384, lo at 32768
#define AHp(s) (smem + (s) * 4096)
#define ALp(s) (smem + 8192 + (s) * 4096)
#define BHp(s) (smem + 16384 + (s) * 8192)
#define BLp(s) (smem + 32768 + (s) * 8192)

    const int tid  = threadIdx.x;
    const int lane = tid & 63;
    const int w    = tid >> 6;
    const int rb   = blockIdx.x * BM;

    const int frow = lane & 15;
    const int fk8  = (lane >> 4) * 8;

    // A staging: r = tid>>3 (0..31), kq = tid&7 -> float4 at k=kq*4 and kq*4+32
    const int ar = tid >> 3;
    const int akq = tid & 7;

    // B staging: wave picks hi/lo and 4 col-octets
    const ushort_t* Tsrc = (w & 1) ? Tl : Th;
    const int boct0 = (w >> 1) * 4;

    f32x4 acc[2];
    acc[0] = (f32x4)0.f; acc[1] = (f32x4)0.f;

    float4 va0, va1;
    const float* Labase = L + (size_t)(rb + ar) * NN + akq * 4;

#define ISSUE_B(c, slot)                                                        \
    {                                                                           \
        const size_t kc = (size_t)(c) * BK;                                     \
        char* bbase = (w & 1) ? BLp(slot) : BHp(slot);                          \
        _Pragma("unroll")                                                       \
        for (int o = 0; o < 4; ++o) {                                           \
            const int oct = boct0 + o;                                          \
            const int col = oct * 8 + (lane >> 3);                              \
            const ushort_t* g = Tsrc + (size_t)col * NN + kc                    \
                                + (((lane & 7) ^ (col & 7)) * 8);               \
            __builtin_amdgcn_global_load_lds((const GLOBAL_AS void*)g,          \
                (LDS_AS void*)(bbase + oct * 1024), 16, 0, 0);                  \
        }                                                                       \
    }

#define LOAD_A(c)                                                               \
    {                                                                           \
        const float* g = Labase + (size_t)(c) * BK;                             \
        va0 = *(const float4*)(g);                                              \
        va1 = *(const float4*)(g + 32);                                         \
    }

#define CONV_WRITE_A(slot)                                                      \
    {                                                                           \
        char* ahb = AHp(slot);                                                  \
        char* alb = ALp(slot);                                                  \
        ushort_t h0, h1, h2, h3, l0, l1, l2, l3;                                \
        f32_split(va0.x, h0, l0); f32_split(va0.y, h1, l1);                     \
        f32_split(va0.z, h2, l2); f32_split(va0.w, h3, l3);                     \
        unsigned a01 = (unsigned)h0 | ((unsigned)h1 << 16);                     \
        unsigned a23 = (unsigned)h2 | ((unsigned)h3 << 16);                     \
        unsigned b01 = (unsigned)l0 | ((unsigned)l1 << 16);                     \
        unsigned b23 = (unsigned)l2 | ((unsigned)l3 << 16);                     \
        const int by0 = (ar * 128 + akq * 8) ^ ((ar & 7) << 4);                 \
        *(uint2*)(ahb + by0) = make_uint2(a01, a23);                            \
        *(uint2*)(alb + by0) = make_uint2(b01, b23);                            \
        f32_split(va1.x, h0, l0); f32_split(va1.y, h1, l1);                     \
        f32_split(va1.z, h2, l2); f32_split(va1.w, h3, l3);                     \
        a01 = (unsigned)h0 | ((unsigned)h1 << 16);                              \
        a23 = (unsigned)h2 | ((unsigned)h3 << 16);                              \
        b01 = (unsigned)l0 | ((unsigned)l1 << 16);                              \
        b23 = (unsigned)l2 | ((unsigned)l3 << 16);                              \
        const int by1 = (ar * 128 + akq * 8 + 64) ^ ((ar & 7) << 4);            \
        *(uint2*)(ahb + by1) = make_uint2(a01, a23);                            \
        *(uint2*)(alb + by1) = make_uint2(b01, b23);                            \
    }

    // ---- prologue
    ISSUE_B(0, 0)
    LOAD_A(0)
    CONV_WRITE_A(0)
    __syncthreads();

    for (int c = 0; c < NC; ++c) {
        const int slot = c & 1;
        if (c + 1 < NC) {
            ISSUE_B(c + 1, slot ^ 1)
            LOAD_A(c + 1)
        }
        {
            const char* ahb = AHp(slot);
            const char* alb = ALp(slot);
            const char* bhb = BHp(slot);
            const char* blb = BLp(slot);
#pragma unroll
            for (int ks = 0; ks < 2; ++ks) {
                const int kk = ks * 32 + fk8;
                bf16x8 Afh[2], Afl[2], Bfh, Bfl;
#pragma unroll
                for (int mt = 0; mt < 2; ++mt) {
                    const int row = mt * 16 + frow;
                    const int off = (row * 128 + kk * 2) ^ ((row & 7) << 4);
                    Afh[mt] = *(const bf16x8*)(ahb + off);
                    Afl[mt] = *(const bf16x8*)(alb + off);
                }
                {
                    const int col = w * 16 + frow;
                    const int off = (col * 128 + kk * 2) ^ ((col & 7) << 4);
                    Bfh = *(const bf16x8*)(bhb + off);
                    Bfl = *(const bf16x8*)(blb + off);
                }
#pragma unroll
                for (int mt = 0; mt < 2; ++mt) {
                    acc[mt] = __builtin_amdgcn_mfma_f32_16x16x32_bf16(
                        Afh[mt], Bfh, acc[mt], 0, 0, 0);
                    acc[mt] = __builtin_amdgcn_mfma_f32_16x16x32_bf16(
                        Afh[mt], Bfl, acc[mt], 0, 0, 0);
                    acc[mt] = __builtin_amdgcn_mfma_f32_16x16x32_bf16(
                        Afl[mt], Bfh, acc[mt], 0, 0, 0);
                }
            }
        }
        if (c + 1 < NC) CONV_WRITE_A(slot ^ 1)
        __syncthreads();
    }

    // ================= fused epilogue (reuse dead LDS) =================
    float* ST  = (float*)(smem + 16384);   // [64][33] floats = 8448 B
    float* WKs = (float*)smem;             // [64][64] floats = 16384 B

    // stage Wk + scatter raw acc into ST[col][row]
    {
        float4* wd = (float4*)WKs;
        const float4* ws = (const float4*)Wk;
#pragma unroll
        for (int j = 0; j < 4; ++j) wd[tid * 4 + j] = ws[tid * 4 + j];

        const int col = w * 16 + frow;
        const int rowb = (lane >> 4) * 4;
#pragma unroll
        for (int mt = 0; mt < 2; ++mt)
#pragma unroll
            for (int r = 0; r < 4; ++r)
                ST[col * 33 + mt * 16 + rowb + r] = acc[mt][r];
    }
    __syncthreads();

    // t = alpha*acc + beta*Tsub ; write back to ST ; optional fp32 store
    {
        const int row = tid >> 3;          // 0..31
        const int c0 = (tid & 7) * 8;
        float tv[8];
#pragma unroll
        for (int j = 0; j < 8; ++j) tv[j] = alpha * ST[(c0 + j) * 33 + row];
        if (beta != 0.f) {
            const size_t o = (size_t)(rb + row) * FF + c0;
            const float4 s0 = *(const float4*)(Tsub + o);
            const float4 s1 = *(const float4*)(Tsub + o + 4);
            tv[0] += beta * s0.x; tv[1] += beta * s0.y;
            tv[2] += beta * s0.z; tv[3] += beta * s0.w;
            tv[4] += beta * s1.x; tv[5] += beta * s1.y;
            tv[6] += beta * s1.z; tv[7] += beta * s1.w;
        }
#pragma unroll
        for (int j = 0; j < 8; ++j) ST[(c0 + j) * 33 + row] = tv[j];
        if (Tstore) {
            const size_t o = (size_t)(rb + row) * FF + c0;
            float4 v0, v1;
            v0.x = tv[0]; v0.y = tv[1]; v0.z = tv[2]; v0.w = tv[3];
            v1.x = tv[4]; v1.y = tv[5]; v1.z = tv[6]; v1.w = tv[7];
            *(float4*)(Tstore + o) = v0;
            *(float4*)(Tstore + o + 4) = v1;
        }
    }
    __syncthreads();

    // split-transpose -> Thn/Tln (B for next hop)
    if (Thn) {
        const int f = tid >> 2;            // 0..63
        const int r0 = (tid & 3) * 8;      // 0..24
        ushort_t hh[8], ll[8];
#pragma unroll
        for (int i = 0; i < 8; ++i) f32_split(ST[f * 33 + r0 + i], hh[i], ll[i]);
        unsigned wh[4], wl[4];
#pragma unroll
        for (int j = 0; j < 4; ++j) {
            wh[j] = (unsigned)hh[2 * j] | ((unsigned)hh[2 * j + 1] << 16);
            wl[j] = (unsigned)ll[2 * j] | ((unsigned)ll[2 * j + 1] << 16);
        }
        const size_t o = (size_t)f * NN + rb + r0;
        *(uint4*)(Thn + o) = make_uint4(wh[0], wh[1], wh[2], wh[3]);
        *(uint4*)(Tln + o) = make_uint4(wl[0], wl[1], wl[2], wl[3]);
    }

    // out += t @ Wk : 1 row x 8 cols per thread
    {
        const int row = tid >> 3;
        const int c0 = (tid & 7) * 8;
        const size_t o = (size_t)(rb + row) * FF + c0;
        float4 a0 = *(const float4*)(out + o);
        float4 a1 = *(const float4*)(out + o + 4);
#pragma unroll
        for (int f = 0; f < FF; ++f) {
            const float s = ST[f * 33 + row];
            const float4 w0 = *(const float4*)&WKs[f * 64 + c0];
            const float4 w1 = *(const float4*)&WKs[f * 64 + c0 + 4];
            a0.x += s * w0.x; a0.y += s * w0.y; a0.z += s * w0.z; a0.w += s * w0.w;
            a1.x += s * w1.x; a1.y += s * w1.y; a1.z += s * w1.z; a1.w += s * w1.w;
        }
        *(float4*)(out + o) = a0;
        *(float4*)(out + o + 4) = a1;
    }
#undef ISSUE_B
#undef LOAD_A
#undef CONV_WRITE_A
#undef AHp
#undef ALp
#undef BHp
#undef BLp
}

extern "C" void kernel_launch(void* const* d_in, const int* in_sizes, int n_in,
                              void* d_out, int out_size, void* d_ws, size_t ws_size,
                              hipStream_t stream)
{
    const float* x    = (const float*)d_in[0];
    const float* L    = (const float*)d_in[1];
    const float* W    = (const float*)d_in[2];   // (4, 64, 64)
    const float* bias = (const float*)d_in[3];
    float* out = (float*)d_out;

    const size_t M1 = (size_t)NN * FF;           // 1,048,576 elems
    float* wsf = (float*)d_ws;
    float* T1 = wsf;                             // 4 MB fp32
    ushort_t* ThA = (ushort_t*)(wsf + M1);       // 2 MB each
    ushort_t* TlA = ThA + M1;
    ushort_t* ThB = TlA + M1;
    ushort_t* TlB = ThB + M1;

    const dim3 gc(NN / 64), bc(256);             // convT_init: 256 blocks
    const dim3 gg(NN / BM), bg(256);             // cheb_hop: 512 blocks

    // hop 0: ThA/TlA = splitT(x) ; out = bias + x@W0
    convT_init<<<gc, bc, 0, stream>>>(x, ThA, TlA, W + 0 * FF * FF, bias, out);
    // hop 1: T1 = L@x ; ThB/TlB = splitT(T1) ; out += T1@W1
    cheb_hop<<<gg, bg, 0, stream>>>(L, ThA, TlA, ThB, TlB, x, T1,
                                    W + 1 * FF * FF, out, 1.f, 0.f);
    // hop 2: T2 = 2*(L@T1) - x ; ThA/TlA = splitT(T2) ; out += T2@W2
    cheb_hop<<<gg, bg, 0, stream>>>(L, ThB, TlB, ThA, TlA, x, nullptr,
                                    W + 2 * FF * FF, out, 2.f, -1.f);
    // hop 3: T3 = 2*(L@T2) - T1 ; out += T3@W3
    cheb_hop<<<gg, bg, 0, stream>>>(L, ThA, TlA, nullptr, nullptr, T1, nullptr,
                                    W + 3 * FF * FF, out, 2.f, -1.f);
}